// Round 5
// baseline (542.809 us; speedup 1.0000x reference)
//
#include <hip/hip_runtime.h>
#include <hip/hip_bf16.h>
#include <math.h>

#define D_MODEL 768
#define D_HID   3072
#define NE      8
#define NTOK    2048
#define NSLOT   (NTOK * 2)
#define RT      128
#define MAXTILES 40

typedef __attribute__((ext_vector_type(8))) short short8;
typedef __attribute__((ext_vector_type(4))) float f32x4;
typedef unsigned short ushort;
typedef unsigned int uint;

// ---- int-region layout (in int units, < 1 MB total) ----
#define I_COUNTS   0
#define I_CURSORS  8
#define I_META     16
#define I_TILEEXP  32
#define I_TILEBASE 72
#define I_PERM     128        // 5120
#define I_SLOTPOS  5248       // 4096
#define I_EID      9344       // 4096
#define I_WSLOT    13440      // 4096 floats
#define I_TROW     17536      // 5120: padded-row -> token (-1 = pad)
#define I_WROW     22656      // 5120 floats: padded-row -> combine weight
// ---- byte offsets, preconv (MFMA) path ----
#define O_XBF   ((size_t)1 << 20)    // 2048x768 bf16 = 3 MB
#define O_H2    ((size_t)4 << 20)    // 5120x3072 bf16 = 30 MB
#define O_W1T   ((size_t)36 << 20)   // [8][3072][768] bf16 = 36 MB
#define O_Y     ((size_t)36 << 20)   // Y fp32 [5120][768] = 15.7 MB — overlays dead w1T
#define O_W2T   ((size_t)72 << 20)   // [8][768][3072] bf16 = 36 MB
#define PRECONV_NEED ((size_t)108 << 20)
// ---- fallback path byte offsets ----
#define F_H_BYTES  ((size_t)1 << 20)
#define F_Y_BYTES  ((size_t)33 << 20)

__device__ inline ushort f2bf(float f) {   // RNE fp32 -> bf16 bits
    uint u = __float_as_uint(f);
    return (ushort)((u + 0x7fffu + ((u >> 16) & 1u)) >> 16);
}

__global__ void k_zero(int* counts) {
    if (threadIdx.x < NE) counts[threadIdx.x] = 0;
}

__global__ void k_router(const float* __restrict__ x, const float* __restrict__ gw,
                         int* __restrict__ counts, int* __restrict__ eid,
                         float* __restrict__ wslot) {
    int n = blockIdx.x;
    int lane = threadIdx.x;
    const float* xr = x + (size_t)n * D_MODEL;
    float acc[NE];
#pragma unroll
    for (int e = 0; e < NE; ++e) acc[e] = 0.f;
    for (int d = lane; d < D_MODEL; d += 64) {
        float xv = xr[d];
        const float* g = gw + (size_t)d * NE;
#pragma unroll
        for (int e = 0; e < NE; ++e) acc[e] += xv * g[e];
    }
#pragma unroll
    for (int e = 0; e < NE; ++e) {
        float v = acc[e];
        for (int off = 32; off; off >>= 1) v += __shfl_down(v, off);
        acc[e] = v;
    }
    if (lane == 0) {
        int e1 = 0; float l1 = acc[0];
        for (int e = 1; e < NE; ++e) if (acc[e] > l1) { l1 = acc[e]; e1 = e; }
        int e2 = -1; float l2 = -1e30f;
        for (int e = 0; e < NE; ++e) if (e != e1 && acc[e] > l2) { l2 = acc[e]; e2 = e; }
        float wa = 1.f / (1.f + expf(l2 - l1));
        float wb = 1.f / (1.f + expf(l1 - l2));
        eid[2 * n] = e1;   eid[2 * n + 1] = e2;
        wslot[2 * n] = wa; wslot[2 * n + 1] = wb;
        atomicAdd(&counts[e1], 1);
        atomicAdd(&counts[e2], 1);
    }
}

__global__ void k_setup(const int* __restrict__ counts, int* __restrict__ cursors,
                        int* __restrict__ meta, int* __restrict__ tileExp,
                        int* __restrict__ tileBase, int* __restrict__ perm,
                        int* __restrict__ trow) {
    __shared__ int tot_s;
    if (threadIdx.x == 0) {
        int off = 0, nt = 0;
        for (int e = 0; e < NE; ++e) {
            cursors[e] = off;
            int t = (counts[e] + RT - 1) / RT;
            for (int i = 0; i < t; ++i) { tileExp[nt] = e; tileBase[nt] = off + i * RT; ++nt; }
            off += t * RT;
        }
        meta[0] = nt;
        meta[1] = off;
        tot_s = off;
    }
    __syncthreads();
    int tot = tot_s;
    for (int i = threadIdx.x; i < tot; i += 256) { perm[i] = -1; trow[i] = -1; }
}

__global__ void k_scatter(const int* __restrict__ eid, const float* __restrict__ wslot,
                          int* __restrict__ cursors, int* __restrict__ perm,
                          int* __restrict__ slotpos, int* __restrict__ trow,
                          float* __restrict__ wrow) {
    int i = blockIdx.x * 256 + threadIdx.x;
    if (i >= NSLOT) return;
    int e = eid[i];
    int pos = atomicAdd(&cursors[e], 1);
    perm[pos] = i;
    slotpos[i] = pos;
    trow[pos] = i >> 1;
    wrow[pos] = wslot[i];
}

// ---------------- convert passes (preconv path) ----------------

__global__ void k_cvt_x(const float* __restrict__ x, ushort* __restrict__ xbf) {
    int i = blockIdx.x * 256 + threadIdx.x;        // over float4s, exact
    float4 v = reinterpret_cast<const float4*>(x)[i];
    ushort4 o = { f2bf(v.x), f2bf(v.y), f2bf(v.z), f2bf(v.w) };
    reinterpret_cast<ushort4*>(xbf)[i] = o;
}

// [E][K][N] fp32 -> [E][N][K] bf16, 64x64 tiles
__global__ __launch_bounds__(256) void k_cvt_wT(const float* __restrict__ src,
                                                ushort* __restrict__ dst,
                                                int K, int N) {
    __shared__ ushort tile[64][72];
    int e = blockIdx.z;
    int n0 = blockIdx.x * 64, k0 = blockIdx.y * 64;
    const float* S = src + (size_t)e * K * N;
    ushort* D = dst + (size_t)e * N * K;
    int t = threadIdx.x;
#pragma unroll
    for (int i = 0; i < 4; ++i) {
        int li = t + 256 * i;          // 0..1023
        int kr = li >> 4;              // 0..63
        int nc = (li & 15) * 4;
        float4 v = *reinterpret_cast<const float4*>(S + (size_t)(k0 + kr) * N + n0 + nc);
        tile[kr][nc + 0] = f2bf(v.x);
        tile[kr][nc + 1] = f2bf(v.y);
        tile[kr][nc + 2] = f2bf(v.z);
        tile[kr][nc + 3] = f2bf(v.w);
    }
    __syncthreads();
#pragma unroll
    for (int i = 0; i < 2; ++i) {
        int li = t + 256 * i;          // 0..511
        int nr = li >> 3;              // 0..63
        int kc = (li & 7) * 8;
        ushort o[8];
#pragma unroll
        for (int j = 0; j < 8; ++j) o[j] = tile[kc + j][nr];
        *reinterpret_cast<uint4*>(D + (size_t)(n0 + nr) * K + k0 + kc) =
            *reinterpret_cast<const uint4*>(o);
    }
}

// ---------------- MFMA GEMMs (64x128 tiles, 4 waves 2x2, wave = 32x64) ----------------
// LDS tiles are [row][K=64] bf16 with T2 XOR swizzle on 16 B chunks:
// chunk' = chunk ^ (row & 7); read side row&7 == lane&7, same involution (rule #21).

#define MFMA16(a, b, c) __builtin_amdgcn_mfma_f32_16x16x32_bf16(a, b, c, 0, 0, 0)

// GEMM1: H[r, :] = gelu(xbf[tok(r)] @ w1T^T + b1)
__global__ __launch_bounds__(256) void k_gemm1_mfma(
    const ushort* __restrict__ xbf, const ushort* __restrict__ w1T,
    const float* __restrict__ b1, const int* __restrict__ meta,
    const int* __restrict__ tileExp, const int* __restrict__ tileBase,
    const int* __restrict__ trow, ushort* __restrict__ H) {
    int tt = blockIdx.y;
    int t = tt >> 1;
    if (t >= meta[0]) return;
    int e = tileExp[t];
    int rb = tileBase[t] + (tt & 1) * 64;
    int cb = blockIdx.x * 128;
    const ushort* __restrict__ B = w1T + (size_t)e * D_HID * D_MODEL;   // [3072][768]

    __shared__ ushort Alds[64 * 64];
    __shared__ ushort Blds[128 * 64];

    int tid = threadIdx.x;
    int tokr[2];
    const ushort* asrc[2];
    ushort* awr[2];
    const ushort* bsrc[4];
    ushort* bwr[4];
#pragma unroll
    for (int i = 0; i < 2; ++i) {
        int li = tid + 256 * i;          // 0..511
        int r = li >> 3, ch = li & 7;
        int tk = trow[rb + r];
        tokr[i] = tk;
        asrc[i] = xbf + (size_t)(tk < 0 ? 0 : tk) * D_MODEL + ch * 8;
        awr[i] = Alds + r * 64 + ((ch ^ (r & 7)) * 8);
    }
#pragma unroll
    for (int i = 0; i < 4; ++i) {
        int li = tid + 256 * i;          // 0..1023
        int r = li >> 3, ch = li & 7;
        bsrc[i] = B + (size_t)(cb + r) * D_MODEL + ch * 8;
        bwr[i] = Blds + r * 64 + ((ch ^ (r & 7)) * 8);
    }

    int lane = tid & 63, w = tid >> 6;
    int wr = w >> 1, wc = w & 1;
    const ushort* aRd = Alds + (wr * 32 + (lane & 15)) * 64;
    const ushort* bRd = Blds + (wc * 64 + (lane & 15)) * 64;
    int swz0 = (((lane >> 4)) ^ (lane & 7)) * 8;
    int swz1 = ((4 + (lane >> 4)) ^ (lane & 7)) * 8;

    f32x4 acc[2][4];
#pragma unroll
    for (int i = 0; i < 2; ++i)
#pragma unroll
        for (int j = 0; j < 4; ++j) acc[i][j] = (f32x4){0.f, 0.f, 0.f, 0.f};

    int4 av[2], bv[4];
#pragma unroll
    for (int i = 0; i < 2; ++i)
        av[i] = (tokr[i] >= 0) ? *reinterpret_cast<const int4*>(asrc[i]) : make_int4(0, 0, 0, 0);
#pragma unroll
    for (int i = 0; i < 4; ++i) bv[i] = *reinterpret_cast<const int4*>(bsrc[i]);

    for (int k0 = 0; k0 < D_MODEL; k0 += 64) {
        __syncthreads();
#pragma unroll
        for (int i = 0; i < 2; ++i) *reinterpret_cast<int4*>(awr[i]) = av[i];
#pragma unroll
        for (int i = 0; i < 4; ++i) *reinterpret_cast<int4*>(bwr[i]) = bv[i];
        __syncthreads();
        if (k0 + 64 < D_MODEL) {
#pragma unroll
            for (int i = 0; i < 2; ++i)
                av[i] = (tokr[i] >= 0) ? *reinterpret_cast<const int4*>(asrc[i] + k0 + 64)
                                       : make_int4(0, 0, 0, 0);
#pragma unroll
            for (int i = 0; i < 4; ++i)
                bv[i] = *reinterpret_cast<const int4*>(bsrc[i] + k0 + 64);
        }
#pragma unroll
        for (int ks = 0; ks < 2; ++ks) {
            int swz = ks ? swz1 : swz0;
            short8 af[2], bfv[4];
#pragma unroll
            for (int fm = 0; fm < 2; ++fm)
                af[fm] = *reinterpret_cast<const short8*>(aRd + fm * 16 * 64 + swz);
#pragma unroll
            for (int fn = 0; fn < 4; ++fn)
                bfv[fn] = *reinterpret_cast<const short8*>(bRd + fn * 16 * 64 + swz);
#pragma unroll
            for (int fm = 0; fm < 2; ++fm)
#pragma unroll
                for (int fn = 0; fn < 4; ++fn)
                    acc[fm][fn] = MFMA16(af[fm], bfv[fn], acc[fm][fn]);
        }
    }

    const float* __restrict__ bias = b1 + (size_t)e * D_HID;
    int r0 = rb + wr * 32, c0 = cb + wc * 64;
#pragma unroll
    for (int fm = 0; fm < 2; ++fm) {
#pragma unroll
        for (int j = 0; j < 4; ++j) {
            int R = r0 + fm * 16 + (lane >> 4) * 4 + j;
#pragma unroll
            for (int fn = 0; fn < 4; ++fn) {
                int C = c0 + fn * 16 + (lane & 15);
                float v = acc[fm][fn][j] + bias[C];
                v = 0.5f * v * (1.f + erff(v * 0.70710678118654752f));
                H[(size_t)R * D_HID + C] = f2bf(v);
            }
        }
    }
}

// GEMM2: Y[r, :] = H[r] @ w2T^T + b2   (plain stores — no atomics)
__global__ __launch_bounds__(256) void k_gemm2_mfma(
    const ushort* __restrict__ H, const ushort* __restrict__ w2T,
    const float* __restrict__ b2, const int* __restrict__ meta,
    const int* __restrict__ tileBase, const int* __restrict__ tileExp,
    float* __restrict__ Y) {
    int tt = blockIdx.y;
    int t = tt >> 1;
    if (t >= meta[0]) return;
    int e = tileExp[t];
    int rb = tileBase[t] + (tt & 1) * 64;
    int cb = blockIdx.x * 128;
    const ushort* __restrict__ B = w2T + (size_t)e * D_MODEL * D_HID;   // [768][3072]

    __shared__ ushort Alds[64 * 64];
    __shared__ ushort Blds[128 * 64];

    int tid = threadIdx.x;
    const ushort* asrc[2];
    ushort* awr[2];
    const ushort* bsrc[4];
    ushort* bwr[4];
#pragma unroll
    for (int i = 0; i < 2; ++i) {
        int li = tid + 256 * i;          // 0..511
        int r = li >> 3, ch = li & 7;
        asrc[i] = H + (size_t)(rb + r) * D_HID + ch * 8;
        awr[i] = Alds + r * 64 + ((ch ^ (r & 7)) * 8);
    }
#pragma unroll
    for (int i = 0; i < 4; ++i) {
        int li = tid + 256 * i;
        int r = li >> 3, ch = li & 7;
        bsrc[i] = B + (size_t)(cb + r) * D_HID + ch * 8;
        bwr[i] = Blds + r * 64 + ((ch ^ (r & 7)) * 8);
    }

    int lane = tid & 63, w = tid >> 6;
    int wr = w >> 1, wc = w & 1;
    const ushort* aRd = Alds + (wr * 32 + (lane & 15)) * 64;
    const ushort* bRd = Blds + (wc * 64 + (lane & 15)) * 64;
    int swz0 = (((lane >> 4)) ^ (lane & 7)) * 8;
    int swz1 = ((4 + (lane >> 4)) ^ (lane & 7)) * 8;

    f32x4 acc[2][4];
#pragma unroll
    for (int i = 0; i < 2; ++i)
#pragma unroll
        for (int j = 0; j < 4; ++j) acc[i][j] = (f32x4){0.f, 0.f, 0.f, 0.f};

    int4 av[2], bv[4];
#pragma unroll
    for (int i = 0; i < 2; ++i) av[i] = *reinterpret_cast<const int4*>(asrc[i]);
#pragma unroll
    for (int i = 0; i < 4; ++i) bv[i] = *reinterpret_cast<const int4*>(bsrc[i]);

    for (int k0 = 0; k0 < D_HID; k0 += 64) {
        __syncthreads();
#pragma unroll
        for (int i = 0; i < 2; ++i) *reinterpret_cast<int4*>(awr[i]) = av[i];
#pragma unroll
        for (int i = 0; i < 4; ++i) *reinterpret_cast<int4*>(bwr[i]) = bv[i];
        __syncthreads();
        if (k0 + 64 < D_HID) {
#pragma unroll
            for (int i = 0; i < 2; ++i)
                av[i] = *reinterpret_cast<const int4*>(asrc[i] + k0 + 64);
#pragma unroll
            for (int i = 0; i < 4; ++i)
                bv[i] = *reinterpret_cast<const int4*>(bsrc[i] + k0 + 64);
        }
#pragma unroll
        for (int ks = 0; ks < 2; ++ks) {
            int swz = ks ? swz1 : swz0;
            short8 af[2], bfv[4];
#pragma unroll
            for (int fm = 0; fm < 2; ++fm)
                af[fm] = *reinterpret_cast<const short8*>(aRd + fm * 16 * 64 + swz);
#pragma unroll
            for (int fn = 0; fn < 4; ++fn)
                bfv[fn] = *reinterpret_cast<const short8*>(bRd + fn * 16 * 64 + swz);
#pragma unroll
            for (int fm = 0; fm < 2; ++fm)
#pragma unroll
                for (int fn = 0; fn < 4; ++fn)
                    acc[fm][fn] = MFMA16(af[fm], bfv[fn], acc[fm][fn]);
        }
    }

    const float* __restrict__ bias = b2 + (size_t)e * D_MODEL;
    int r0 = rb + wr * 32, c0 = cb + wc * 64;
#pragma unroll
    for (int fm = 0; fm < 2; ++fm) {
#pragma unroll
        for (int j = 0; j < 4; ++j) {
            int R = r0 + fm * 16 + (lane >> 4) * 4 + j;
            float* yrow = Y + (size_t)R * D_MODEL;
#pragma unroll
            for (int fn = 0; fn < 4; ++fn) {
                int C = c0 + fn * 16 + (lane & 15);
                yrow[C] = acc[fm][fn][j] + bias[C];
            }
        }
    }
}

// out[n] = w0 * Y[pos(n,0)] + w1 * Y[pos(n,1)]   (float4-vectorized)
__global__ void k_combine(const float* __restrict__ Y, const int* __restrict__ slotpos,
                          const float* __restrict__ wslot, float* __restrict__ out) {
    int n = blockIdx.x;
    int p0 = slotpos[2 * n], p1 = slotpos[2 * n + 1];
    float w0 = wslot[2 * n], w1 = wslot[2 * n + 1];
    const float4* y0 = reinterpret_cast<const float4*>(Y + (size_t)p0 * D_MODEL);
    const float4* y1 = reinterpret_cast<const float4*>(Y + (size_t)p1 * D_MODEL);
    float4* o = reinterpret_cast<float4*>(out + (size_t)n * D_MODEL);
    int c = threadIdx.x;                 // 192 threads, 192 float4 = 768 floats
    float4 a = y0[c], b = y1[c];
    o[c] = make_float4(w0 * a.x + w1 * b.x, w0 * a.y + w1 * b.y,
                       w0 * a.z + w1 * b.z, w0 * a.w + w1 * b.w);
}

// ---------------- fallback SIMT path (round-1, verified) ----------------

__global__ __launch_bounds__(256) void k_gemm1(
    const float* __restrict__ x, const float* __restrict__ w1,
    const float* __restrict__ b1, const int* __restrict__ meta,
    const int* __restrict__ tileExp, const int* __restrict__ tileBase,
    const int* __restrict__ perm, __hip_bfloat16* __restrict__ H) {
    int t = blockIdx.y;
    if (t >= meta[0]) return;
    int e = tileExp[t];
    int rb = tileBase[t];
    int cb = blockIdx.x * 128;
    const float* __restrict__ B = w1 + (size_t)e * D_MODEL * D_HID;
    __shared__ float As[16][132];
    __shared__ float Bs[16][132];
    int tid = threadIdx.x;
    int tx = tid & 15, ty = tid >> 4;
    int arow = tid >> 4, akk = tid & 15;
    int bc = tid & 127, bkr = tid >> 7;
    int tok[8];
#pragma unroll
    for (int p = 0; p < 8; ++p) {
        int s = perm[rb + arow + 16 * p];
        tok[p] = (s >= 0) ? (s >> 1) : -1;
    }
    float acc[8][8];
#pragma unroll
    for (int i = 0; i < 8; ++i)
#pragma unroll
        for (int j = 0; j < 8; ++j) acc[i][j] = 0.f;
    for (int k0 = 0; k0 < D_MODEL; k0 += 16) {
#pragma unroll
        for (int p = 0; p < 8; ++p) {
            float v = 0.f;
            if (tok[p] >= 0) v = x[(size_t)tok[p] * D_MODEL + k0 + akk];
            As[akk][arow + 16 * p] = v;
        }
#pragma unroll
        for (int p = 0; p < 8; ++p) {
            int kk = bkr + 2 * p;
            Bs[kk][bc] = B[(size_t)(k0 + kk) * D_HID + cb + bc];
        }
        __syncthreads();
#pragma unroll
        for (int kk = 0; kk < 16; ++kk) {
            float4 aA = *reinterpret_cast<const float4*>(&As[kk][ty * 4]);
            float4 aB = *reinterpret_cast<const float4*>(&As[kk][ty * 4 + 64]);
            float4 bA = *reinterpret_cast<const float4*>(&Bs[kk][tx * 4]);
            float4 bB = *reinterpret_cast<const float4*>(&Bs[kk][tx * 4 + 64]);
            float a[8] = {aA.x, aA.y, aA.z, aA.w, aB.x, aB.y, aB.z, aB.w};
            float b[8] = {bA.x, bA.y, bA.z, bA.w, bB.x, bB.y, bB.z, bB.w};
#pragma unroll
            for (int i = 0; i < 8; ++i)
#pragma unroll
                for (int j = 0; j < 8; ++j) acc[i][j] = fmaf(a[i], b[j], acc[i][j]);
        }
        __syncthreads();
    }
    const float* __restrict__ bias = b1 + (size_t)e * D_HID;
#pragma unroll
    for (int i = 0; i < 8; ++i) {
        int r = rb + ty * 4 + (i & 3) + ((i >> 2) << 6);
#pragma unroll
        for (int j = 0; j < 8; ++j) {
            int c = cb + tx * 4 + (j & 3) + ((j >> 2) << 6);
            float v = acc[i][j] + bias[c];
            v = 0.5f * v * (1.f + erff(v * 0.70710678118654752f));
            H[(size_t)r * D_HID + c] = __float2bfloat16(v);
        }
    }
}

__global__ __launch_bounds__(256) void k_gemm2(
    const __hip_bfloat16* __restrict__ H, const float* __restrict__ w2,
    const float* __restrict__ b2, const int* __restrict__ meta,
    const int* __restrict__ tileExp, const int* __restrict__ tileBase,
    float* __restrict__ Y) {
    int t = blockIdx.y;
    if (t >= meta[0]) return;
    int e = tileExp[t];
    int rb = tileBase[t];
    int cb = blockIdx.x * 128;
    const float* __restrict__ B = w2 + (size_t)e * D_HID * D_MODEL;
    __shared__ float As[16][132];
    __shared__ float Bs[16][132];
    int tid = threadIdx.x;
    int tx = tid & 15, ty = tid >> 4;
    int arow = tid >> 4, akk = tid & 15;
    int bc = tid & 127, bkr = tid >> 7;
    float acc[8][8];
#pragma unroll
    for (int i = 0; i < 8; ++i)
#pragma unroll
        for (int j = 0; j < 8; ++j) acc[i][j] = 0.f;
    for (int k0 = 0; k0 < D_HID; k0 += 16) {
#pragma unroll
        for (int p = 0; p < 8; ++p) {
            int r = rb + arow + 16 * p;
            As[akk][arow + 16 * p] = __bfloat162float(H[(size_t)r * D_HID + k0 + akk]);
        }
#pragma unroll
        for (int p = 0; p < 8; ++p) {
            int kk = bkr + 2 * p;
            Bs[kk][bc] = B[(size_t)(k0 + kk) * D_MODEL + cb + bc];
        }
        __syncthreads();
#pragma unroll
        for (int kk = 0; kk < 16; ++kk) {
            float4 aA = *reinterpret_cast<const float4*>(&As[kk][ty * 4]);
            float4 aB = *reinterpret_cast<const float4*>(&As[kk][ty * 4 + 64]);
            float4 bA = *reinterpret_cast<const float4*>(&Bs[kk][tx * 4]);
            float4 bB = *reinterpret_cast<const float4*>(&Bs[kk][tx * 4 + 64]);
            float a[8] = {aA.x, aA.y, aA.z, aA.w, aB.x, aB.y, aB.z, aB.w};
            float b[8] = {bA.x, bA.y, bA.z, bA.w, bB.x, bB.y, bB.z, bB.w};
#pragma unroll
            for (int i = 0; i < 8; ++i)
#pragma unroll
                for (int j = 0; j < 8; ++j) acc[i][j] = fmaf(a[i], b[j], acc[i][j]);
        }
        __syncthreads();
    }
    const float* __restrict__ bias = b2 + (size_t)e * D_MODEL;
#pragma unroll
    for (int i = 0; i < 8; ++i) {
        int r = rb + ty * 4 + (i & 3) + ((i >> 2) << 6);
#pragma unroll
        for (int j = 0; j < 8; ++j) {
            int c = cb + tx * 4 + (j & 3) + ((j >> 2) << 6);
            Y[(size_t)r * D_MODEL + c] = acc[i][j] + bias[c];
        }
    }
}

__global__ void k_combine_f(const float* __restrict__ Y, const int* __restrict__ slotpos,
                            const float* __restrict__ wslot, float* __restrict__ out) {
    int n = blockIdx.x;
    int p0 = slotpos[2 * n], p1 = slotpos[2 * n + 1];
    float w0 = wslot[2 * n], w1 = wslot[2 * n + 1];
    const float* y0 = Y + (size_t)p0 * D_MODEL;
    const float* y1 = Y + (size_t)p1 * D_MODEL;
    float* o = out + (size_t)n * D_MODEL;
    for (int c = threadIdx.x; c < D_MODEL; c += 256)
        o[c] = w0 * y0[c] + w1 * y1[c];
}

extern "C" void kernel_launch(void* const* d_in, const int* in_sizes, int n_in,
                              void* d_out, int out_size, void* d_ws, size_t ws_size,
                              hipStream_t stream) {
    const float* x  = (const float*)d_in[0];
    const float* gw = (const float*)d_in[1];
    const float* w1 = (const float*)d_in[2];
    const float* b1 = (const float*)d_in[3];
    const float* w2 = (const float*)d_in[4];
    const float* b2 = (const float*)d_in[5];
    float* out = (float*)d_out;
    int*   wsi = (int*)d_ws;
    float* wsf = (float*)d_ws;

    k_zero<<<1, 64, 0, stream>>>(wsi + I_COUNTS);
    k_router<<<NTOK, 64, 0, stream>>>(x, gw, wsi + I_COUNTS, wsi + I_EID, wsf + I_WSLOT);
    k_setup<<<1, 256, 0, stream>>>(wsi + I_COUNTS, wsi + I_CURSORS, wsi + I_META,
                                   wsi + I_TILEEXP, wsi + I_TILEBASE, wsi + I_PERM,
                                   wsi + I_TROW);
    k_scatter<<<(NSLOT + 255) / 256, 256, 0, stream>>>(
        wsi + I_EID, wsf + I_WSLOT, wsi + I_CURSORS, wsi + I_PERM,
        wsi + I_SLOTPOS, wsi + I_TROW, wsf + I_WROW);

    if (ws_size >= PRECONV_NEED) {
        ushort* xbf = (ushort*)((char*)d_ws + O_XBF);
        ushort* H2  = (ushort*)((char*)d_ws + O_H2);
        ushort* w1T = (ushort*)((char*)d_ws + O_W1T);
        ushort* w2T = (ushort*)((char*)d_ws + O_W2T);
        float*  Y   = (float*)((char*)d_ws + O_Y);    // overlays w1T (dead after gemm1)
        k_cvt_x<<<(NTOK * D_MODEL / 4) / 256, 256, 0, stream>>>(x, xbf);
        k_cvt_wT<<<dim3(D_HID / 64, D_MODEL / 64, NE), 256, 0, stream>>>(w1, w1T, D_MODEL, D_HID);
        k_cvt_wT<<<dim3(D_MODEL / 64, D_HID / 64, NE), 256, 0, stream>>>(w2, w2T, D_HID, D_MODEL);
        k_gemm1_mfma<<<dim3(D_HID / 128, 2 * MAXTILES), 256, 0, stream>>>(
            xbf, w1T, b1, wsi + I_META, wsi + I_TILEEXP, wsi + I_TILEBASE,
            wsi + I_TROW, H2);
        k_gemm2_mfma<<<dim3(D_MODEL / 128, 2 * MAXTILES), 256, 0, stream>>>(
            H2, w2T, b2, wsi + I_META, wsi + I_TILEBASE, wsi + I_TILEEXP, Y);
        k_combine<<<NTOK, 192, 0, stream>>>(Y, wsi + I_SLOTPOS, wsf + I_WSLOT, out);
    } else {
        __hip_bfloat16* H = (__hip_bfloat16*)((char*)d_ws + F_H_BYTES);
        float*          Y = (float*)((char*)d_ws + F_Y_BYTES);
        k_gemm1<<<dim3(D_HID / 128, MAXTILES), 256, 0, stream>>>(
            x, w1, b1, wsi + I_META, wsi + I_TILEEXP, wsi + I_TILEBASE,
            wsi + I_PERM, H);
        k_gemm2<<<dim3(D_MODEL / 128, MAXTILES), 256, 0, stream>>>(
            H, w2, b2, wsi + I_META, wsi + I_TILEEXP, wsi + I_TILEBASE, Y);
        k_combine_f<<<NTOK, 256, 0, stream>>>(Y, wsi + I_SLOTPOS, wsf + I_WSLOT, out);
    }
}

// Round 6
// 537.233 us; speedup vs baseline: 1.0104x; 1.0104x over previous
//
#include <hip/hip_runtime.h>
#include <hip/hip_bf16.h>
#include <math.h>

#define D_MODEL 768
#define D_HID   3072
#define NE      8
#define NTOK    2048
#define NSLOT   (NTOK * 2)
#define RT      128
#define MAXTILES 40
#define MAXROWS  5120

typedef __attribute__((ext_vector_type(8))) short short8;
typedef __attribute__((ext_vector_type(4))) float f32x4;
typedef unsigned short ushort;
typedef unsigned int uint;

// ---- int-region layout (in int units, < 1 MB total) ----
#define I_COUNTS   0
#define I_CURSORS  8
#define I_META     16
#define I_TILEEXP  32
#define I_TILEBASE 72
#define I_PERM     128        // 5120
#define I_SLOTPOS  5248       // 4096
#define I_EID      9344       // 4096
#define I_WSLOT    13440      // 4096 floats
#define I_TROW     17536      // 5120: padded-row -> token (-1 = pad)
#define I_WROW     22656      // 5120 floats (fallback only)
// ---- byte offsets, preconv (MFMA) path ----
#define O_XBF   ((size_t)1 << 20)    // 2048x768 bf16 = 3 MB
#define O_H2    ((size_t)4 << 20)    // 5120x3072 bf16 = 30 MB
#define O_W1T   ((size_t)36 << 20)   // [8][3072][768] bf16 = 36 MB (dead after gemm1)
#define O_YP    ((size_t)36 << 20)   // 4 x bf16 [5120][768] partials = 30 MB, overlays w1T
#define O_W2T   ((size_t)72 << 20)   // [8][768][3072] bf16 = 36 MB
#define PRECONV_NEED ((size_t)108 << 20)
#define YPS     ((size_t)MAXROWS * D_MODEL)    // partial-buffer stride in ushorts
// ---- fallback path byte offsets ----
#define F_H_BYTES  ((size_t)1 << 20)
#define F_Y_BYTES  ((size_t)33 << 20)

__device__ inline ushort f2bf(float f) {   // RNE fp32 -> bf16 bits
    uint u = __float_as_uint(f);
    return (ushort)((u + 0x7fffu + ((u >> 16) & 1u)) >> 16);
}
__device__ inline float bf2f(ushort u) {
    return __uint_as_float(((uint)u) << 16);
}

__global__ void k_zero(int* counts) {
    if (threadIdx.x < NE) counts[threadIdx.x] = 0;
}

__global__ void k_initrows(int* __restrict__ perm, int* __restrict__ trow) {
    int i = blockIdx.x * 256 + threadIdx.x;    // 20*256 = 5120 exact
    perm[i] = -1;
    trow[i] = -1;
}

__global__ void k_router(const float* __restrict__ x, const float* __restrict__ gw,
                         int* __restrict__ counts, int* __restrict__ eid,
                         float* __restrict__ wslot) {
    int n = blockIdx.x;
    int lane = threadIdx.x;
    const float* xr = x + (size_t)n * D_MODEL;
    float acc[NE];
#pragma unroll
    for (int e = 0; e < NE; ++e) acc[e] = 0.f;
    for (int d = lane; d < D_MODEL; d += 64) {
        float xv = xr[d];
        const float* g = gw + (size_t)d * NE;
#pragma unroll
        for (int e = 0; e < NE; ++e) acc[e] += xv * g[e];
    }
#pragma unroll
    for (int e = 0; e < NE; ++e) {
        float v = acc[e];
        for (int off = 32; off; off >>= 1) v += __shfl_down(v, off);
        acc[e] = v;
    }
    if (lane == 0) {
        int e1 = 0; float l1 = acc[0];
        for (int e = 1; e < NE; ++e) if (acc[e] > l1) { l1 = acc[e]; e1 = e; }
        int e2 = -1; float l2 = -1e30f;
        for (int e = 0; e < NE; ++e) if (e != e1 && acc[e] > l2) { l2 = acc[e]; e2 = e; }
        float wa = 1.f / (1.f + expf(l2 - l1));
        float wb = 1.f / (1.f + expf(l1 - l2));
        eid[2 * n] = e1;   eid[2 * n + 1] = e2;
        wslot[2 * n] = wa; wslot[2 * n + 1] = wb;
        atomicAdd(&counts[e1], 1);
        atomicAdd(&counts[e2], 1);
    }
}

__global__ void k_setup(const int* __restrict__ counts, int* __restrict__ cursors,
                        int* __restrict__ meta, int* __restrict__ tileExp,
                        int* __restrict__ tileBase) {
    if (threadIdx.x == 0) {
        int off = 0, nt = 0;
        for (int e = 0; e < NE; ++e) {
            cursors[e] = off;
            int t = (counts[e] + RT - 1) / RT;
            for (int i = 0; i < t; ++i) { tileExp[nt] = e; tileBase[nt] = off + i * RT; ++nt; }
            off += t * RT;
        }
        meta[0] = nt;
        meta[1] = off;
    }
}

__global__ void k_scatter(const int* __restrict__ eid, const float* __restrict__ wslot,
                          int* __restrict__ cursors, int* __restrict__ perm,
                          int* __restrict__ slotpos, int* __restrict__ trow,
                          float* __restrict__ wrow) {
    int i = blockIdx.x * 256 + threadIdx.x;
    if (i >= NSLOT) return;
    int e = eid[i];
    int pos = atomicAdd(&cursors[e], 1);
    perm[pos] = i;
    slotpos[i] = pos;
    trow[pos] = i >> 1;
    wrow[pos] = wslot[i];
}

// ---------------- convert passes (preconv path) ----------------

__global__ void k_cvt_x(const float* __restrict__ x, ushort* __restrict__ xbf) {
    int i = blockIdx.x * 256 + threadIdx.x;        // over float4s, exact
    float4 v = reinterpret_cast<const float4*>(x)[i];
    ushort4 o = { f2bf(v.x), f2bf(v.y), f2bf(v.z), f2bf(v.w) };
    reinterpret_cast<ushort4*>(xbf)[i] = o;
}

// [E][K][N] fp32 -> [E][N][K] bf16, 64x64 tiles
__global__ __launch_bounds__(256) void k_cvt_wT(const float* __restrict__ src,
                                                ushort* __restrict__ dst,
                                                int K, int N) {
    __shared__ ushort tile[64][72];
    int e = blockIdx.z;
    int n0 = blockIdx.x * 64, k0 = blockIdx.y * 64;
    const float* S = src + (size_t)e * K * N;
    ushort* D = dst + (size_t)e * N * K;
    int t = threadIdx.x;
#pragma unroll
    for (int i = 0; i < 4; ++i) {
        int li = t + 256 * i;          // 0..1023
        int kr = li >> 4;              // 0..63
        int nc = (li & 15) * 4;
        float4 v = *reinterpret_cast<const float4*>(S + (size_t)(k0 + kr) * N + n0 + nc);
        tile[kr][nc + 0] = f2bf(v.x);
        tile[kr][nc + 1] = f2bf(v.y);
        tile[kr][nc + 2] = f2bf(v.z);
        tile[kr][nc + 3] = f2bf(v.w);
    }
    __syncthreads();
#pragma unroll
    for (int i = 0; i < 2; ++i) {
        int li = t + 256 * i;          // 0..511
        int nr = li >> 3;              // 0..63
        int kc = (li & 7) * 8;
        ushort o[8];
#pragma unroll
        for (int j = 0; j < 8; ++j) o[j] = tile[kc + j][nr];
        *reinterpret_cast<uint4*>(D + (size_t)(n0 + nr) * K + k0 + kc) =
            *reinterpret_cast<const uint4*>(o);
    }
}

// ---------------- MFMA GEMMs ----------------
// LDS tiles [row][K=64] bf16, T2 XOR swizzle on 16 B chunks: chunk' = chunk ^ (row&7);
// read side row&7 == lane&7 -> same involution both sides (rule #21). Verified R3/R5.
// XCD swizzle (T1): flat grid, nwg % 8 == 0, swz = (bid&7)*(nwg/8) + (bid>>3).

#define MFMA16(a, b, c) __builtin_amdgcn_mfma_f32_16x16x32_bf16(a, b, c, 0, 0, 0)

// GEMM1: H[r, :] = gelu(xbf[tok(r)] @ w1T^T + b1)   (128x128 tile, 4 waves 2x2)
__global__ __launch_bounds__(256) void k_gemm1_mfma(
    const ushort* __restrict__ xbf, const ushort* __restrict__ w1T,
    const float* __restrict__ b1, const int* __restrict__ meta,
    const int* __restrict__ tileExp, const int* __restrict__ tileBase,
    const int* __restrict__ trow, ushort* __restrict__ H) {
    const int NWG = (D_HID / 128) * MAXTILES;        // 960
    int bid = blockIdx.x;
    int swz = (bid & 7) * (NWG / 8) + (bid >> 3);    // t-major chunks per XCD
    int t = swz / (D_HID / 128);
    int cb = (swz % (D_HID / 128)) * 128;
    if (t >= meta[0]) return;
    int e = tileExp[t], rb = tileBase[t];
    const ushort* __restrict__ B = w1T + (size_t)e * D_HID * D_MODEL;   // [3072][768]

    __shared__ ushort Alds[128 * 64];
    __shared__ ushort Blds[128 * 64];

    int tid = threadIdx.x;
    int tokr[4];
    const ushort* asrc[4];
    const ushort* bsrc[4];
    ushort* awr[4];
    ushort* bwr[4];
#pragma unroll
    for (int i = 0; i < 4; ++i) {
        int li = tid + 256 * i;          // 0..1023
        int r = li >> 3, ch = li & 7;
        int tk = trow[rb + r];
        tokr[i] = tk;
        asrc[i] = xbf + (size_t)(tk < 0 ? 0 : tk) * D_MODEL + ch * 8;
        bsrc[i] = B + (size_t)(cb + r) * D_MODEL + ch * 8;
        int off = r * 64 + ((ch ^ (r & 7)) * 8);
        awr[i] = Alds + off;
        bwr[i] = Blds + off;
    }

    int lane = tid & 63, w = tid >> 6;
    int wr = w >> 1, wc = w & 1;
    const ushort* aRd = Alds + (wr * 64 + (lane & 15)) * 64;
    const ushort* bRd = Blds + (wc * 64 + (lane & 15)) * 64;
    int swz0 = (((lane >> 4)) ^ (lane & 7)) * 8;
    int swz1 = ((4 + (lane >> 4)) ^ (lane & 7)) * 8;

    f32x4 acc[4][4];
#pragma unroll
    for (int i = 0; i < 4; ++i)
#pragma unroll
        for (int j = 0; j < 4; ++j) acc[i][j] = (f32x4){0.f, 0.f, 0.f, 0.f};

    int4 av[4], bv[4];
#pragma unroll
    for (int i = 0; i < 4; ++i) {
        av[i] = (tokr[i] >= 0) ? *reinterpret_cast<const int4*>(asrc[i]) : make_int4(0, 0, 0, 0);
        bv[i] = *reinterpret_cast<const int4*>(bsrc[i]);
    }

    for (int k0 = 0; k0 < D_MODEL; k0 += 64) {
        __syncthreads();
#pragma unroll
        for (int i = 0; i < 4; ++i) {
            *reinterpret_cast<int4*>(awr[i]) = av[i];
            *reinterpret_cast<int4*>(bwr[i]) = bv[i];
        }
        __syncthreads();
        if (k0 + 64 < D_MODEL) {
#pragma unroll
            for (int i = 0; i < 4; ++i) {
                av[i] = (tokr[i] >= 0) ? *reinterpret_cast<const int4*>(asrc[i] + k0 + 64)
                                       : make_int4(0, 0, 0, 0);
                bv[i] = *reinterpret_cast<const int4*>(bsrc[i] + k0 + 64);
            }
        }
#pragma unroll
        for (int ks = 0; ks < 2; ++ks) {
            int swzo = ks ? swz1 : swz0;
            short8 af[4], bfv[4];
#pragma unroll
            for (int fm = 0; fm < 4; ++fm)
                af[fm] = *reinterpret_cast<const short8*>(aRd + fm * 16 * 64 + swzo);
#pragma unroll
            for (int fn = 0; fn < 4; ++fn)
                bfv[fn] = *reinterpret_cast<const short8*>(bRd + fn * 16 * 64 + swzo);
#pragma unroll
            for (int fm = 0; fm < 4; ++fm)
#pragma unroll
                for (int fn = 0; fn < 4; ++fn)
                    acc[fm][fn] = MFMA16(af[fm], bfv[fn], acc[fm][fn]);
        }
    }

    const float* __restrict__ bias = b1 + (size_t)e * D_HID;
    int r0 = rb + wr * 64, c0 = cb + wc * 64;
#pragma unroll
    for (int fm = 0; fm < 4; ++fm) {
#pragma unroll
        for (int j = 0; j < 4; ++j) {
            int R = r0 + fm * 16 + (lane >> 4) * 4 + j;
#pragma unroll
            for (int fn = 0; fn < 4; ++fn) {
                int C = c0 + fn * 16 + (lane & 15);
                float v = acc[fm][fn][j] + bias[C];
                v = 0.5f * v * (1.f + erff(v * 0.70710678118654752f));
                H[(size_t)R * D_HID + C] = f2bf(v);
            }
        }
    }
}

// GEMM2 split-K=4: Yp[kc][r, :] = H[r, kc*768:(kc+1)*768] @ w2T^T (+b2 if kc==0), bf16
// 64x128 tile, 4 waves 2x2
__global__ __launch_bounds__(256) void k_gemm2_mfma(
    const ushort* __restrict__ H, const ushort* __restrict__ w2T,
    const float* __restrict__ b2, const int* __restrict__ meta,
    const int* __restrict__ tileBase, const int* __restrict__ tileExp,
    ushort* __restrict__ Yp) {
    const int NWG = (D_MODEL / 128) * (2 * MAXTILES) * 4;   // 1920
    int bid = blockIdx.x;
    int swz = (bid & 7) * (NWG / 8) + (bid >> 3);
    int kc  = swz / 480;
    int rem = swz % 480;
    int tt  = rem / 6;
    int cb  = (rem % 6) * 128;
    int t = tt >> 1;
    if (t >= meta[0]) return;
    int e = tileExp[t];
    int rb = tileBase[t] + (tt & 1) * 64;
    int kbase = kc * 768;
    const ushort* __restrict__ B = w2T + (size_t)e * D_MODEL * D_HID;   // [768][3072]

    __shared__ ushort Alds[64 * 64];
    __shared__ ushort Blds[128 * 64];

    int tid = threadIdx.x;
    const ushort* asrc[2];
    ushort* awr[2];
    const ushort* bsrc[4];
    ushort* bwr[4];
#pragma unroll
    for (int i = 0; i < 2; ++i) {
        int li = tid + 256 * i;          // 0..511
        int r = li >> 3, ch = li & 7;
        asrc[i] = H + (size_t)(rb + r) * D_HID + kbase + ch * 8;
        awr[i] = Alds + r * 64 + ((ch ^ (r & 7)) * 8);
    }
#pragma unroll
    for (int i = 0; i < 4; ++i) {
        int li = tid + 256 * i;
        int r = li >> 3, ch = li & 7;
        bsrc[i] = B + (size_t)(cb + r) * D_HID + kbase + ch * 8;
        bwr[i] = Blds + r * 64 + ((ch ^ (r & 7)) * 8);
    }

    int lane = tid & 63, w = tid >> 6;
    int wr = w >> 1, wc = w & 1;
    const ushort* aRd = Alds + (wr * 32 + (lane & 15)) * 64;
    const ushort* bRd = Blds + (wc * 64 + (lane & 15)) * 64;
    int swz0 = (((lane >> 4)) ^ (lane & 7)) * 8;
    int swz1 = ((4 + (lane >> 4)) ^ (lane & 7)) * 8;

    f32x4 acc[2][4];
#pragma unroll
    for (int i = 0; i < 2; ++i)
#pragma unroll
        for (int j = 0; j < 4; ++j) acc[i][j] = (f32x4){0.f, 0.f, 0.f, 0.f};

    int4 av[2], bv[4];
#pragma unroll
    for (int i = 0; i < 2; ++i) av[i] = *reinterpret_cast<const int4*>(asrc[i]);
#pragma unroll
    for (int i = 0; i < 4; ++i) bv[i] = *reinterpret_cast<const int4*>(bsrc[i]);

    for (int k0 = 0; k0 < 768; k0 += 64) {
        __syncthreads();
#pragma unroll
        for (int i = 0; i < 2; ++i) *reinterpret_cast<int4*>(awr[i]) = av[i];
#pragma unroll
        for (int i = 0; i < 4; ++i) *reinterpret_cast<int4*>(bwr[i]) = bv[i];
        __syncthreads();
        if (k0 + 64 < 768) {
#pragma unroll
            for (int i = 0; i < 2; ++i)
                av[i] = *reinterpret_cast<const int4*>(asrc[i] + k0 + 64);
#pragma unroll
            for (int i = 0; i < 4; ++i)
                bv[i] = *reinterpret_cast<const int4*>(bsrc[i] + k0 + 64);
        }
#pragma unroll
        for (int ks = 0; ks < 2; ++ks) {
            int swzo = ks ? swz1 : swz0;
            short8 af[2], bfv[4];
#pragma unroll
            for (int fm = 0; fm < 2; ++fm)
                af[fm] = *reinterpret_cast<const short8*>(aRd + fm * 16 * 64 + swzo);
#pragma unroll
            for (int fn = 0; fn < 4; ++fn)
                bfv[fn] = *reinterpret_cast<const short8*>(bRd + fn * 16 * 64 + swzo);
#pragma unroll
            for (int fm = 0; fm < 2; ++fm)
#pragma unroll
                for (int fn = 0; fn < 4; ++fn)
                    acc[fm][fn] = MFMA16(af[fm], bfv[fn], acc[fm][fn]);
        }
    }

    const float* __restrict__ bias = b2 + (size_t)e * D_MODEL;
    ushort* __restrict__ Yk = Yp + (size_t)kc * YPS;
    int r0 = rb + wr * 32, c0 = cb + wc * 64;
#pragma unroll
    for (int fm = 0; fm < 2; ++fm) {
#pragma unroll
        for (int j = 0; j < 4; ++j) {
            int R = r0 + fm * 16 + (lane >> 4) * 4 + j;
            ushort* yrow = Yk + (size_t)R * D_MODEL;
#pragma unroll
            for (int fn = 0; fn < 4; ++fn) {
                int C = c0 + fn * 16 + (lane & 15);
                float bb = (kc == 0) ? bias[C] : 0.f;
                yrow[C] = f2bf(acc[fm][fn][j] + bb);
            }
        }
    }
}

// out[n] = w0 * sum_kc Yp[kc][p0] + w1 * sum_kc Yp[kc][p1]
__global__ void k_combine(const ushort* __restrict__ Yp, const int* __restrict__ slotpos,
                          const float* __restrict__ wslot, float* __restrict__ out) {
    int n = blockIdx.x;
    int c = threadIdx.x;                 // 192 threads x 4 cols
    int p0 = slotpos[2 * n], p1 = slotpos[2 * n + 1];
    float w0 = wslot[2 * n], w1 = wslot[2 * n + 1];
    float s0[4] = {0.f, 0.f, 0.f, 0.f};
    float s1[4] = {0.f, 0.f, 0.f, 0.f};
#pragma unroll
    for (int kc = 0; kc < 4; ++kc) {
        const ushort* Yk = Yp + (size_t)kc * YPS;
        ushort4 u0 = *reinterpret_cast<const ushort4*>(Yk + (size_t)p0 * D_MODEL + c * 4);
        ushort4 u1 = *reinterpret_cast<const ushort4*>(Yk + (size_t)p1 * D_MODEL + c * 4);
        s0[0] += bf2f(u0.x); s0[1] += bf2f(u0.y); s0[2] += bf2f(u0.z); s0[3] += bf2f(u0.w);
        s1[0] += bf2f(u1.x); s1[1] += bf2f(u1.y); s1[2] += bf2f(u1.z); s1[3] += bf2f(u1.w);
    }
    float4 o = make_float4(w0 * s0[0] + w1 * s1[0], w0 * s0[1] + w1 * s1[1],
                           w0 * s0[2] + w1 * s1[2], w0 * s0[3] + w1 * s1[3]);
    *reinterpret_cast<float4*>(out + (size_t)n * D_MODEL + c * 4) = o;
}

// ---------------- fallback SIMT path (round-1, verified) ----------------

__global__ __launch_bounds__(256) void k_gemm1(
    const float* __restrict__ x, const float* __restrict__ w1,
    const float* __restrict__ b1, const int* __restrict__ meta,
    const int* __restrict__ tileExp, const int* __restrict__ tileBase,
    const int* __restrict__ perm, __hip_bfloat16* __restrict__ H) {
    int t = blockIdx.y;
    if (t >= meta[0]) return;
    int e = tileExp[t];
    int rb = tileBase[t];
    int cb = blockIdx.x * 128;
    const float* __restrict__ B = w1 + (size_t)e * D_MODEL * D_HID;
    __shared__ float As[16][132];
    __shared__ float Bs[16][132];
    int tid = threadIdx.x;
    int tx = tid & 15, ty = tid >> 4;
    int arow = tid >> 4, akk = tid & 15;
    int bc = tid & 127, bkr = tid >> 7;
    int tok[8];
#pragma unroll
    for (int p = 0; p < 8; ++p) {
        int s = perm[rb + arow + 16 * p];
        tok[p] = (s >= 0) ? (s >> 1) : -1;
    }
    float acc[8][8];
#pragma unroll
    for (int i = 0; i < 8; ++i)
#pragma unroll
        for (int j = 0; j < 8; ++j) acc[i][j] = 0.f;
    for (int k0 = 0; k0 < D_MODEL; k0 += 16) {
#pragma unroll
        for (int p = 0; p < 8; ++p) {
            float v = 0.f;
            if (tok[p] >= 0) v = x[(size_t)tok[p] * D_MODEL + k0 + akk];
            As[akk][arow + 16 * p] = v;
        }
#pragma unroll
        for (int p = 0; p < 8; ++p) {
            int kk = bkr + 2 * p;
            Bs[kk][bc] = B[(size_t)(k0 + kk) * D_HID + cb + bc];
        }
        __syncthreads();
#pragma unroll
        for (int kk = 0; kk < 16; ++kk) {
            float4 aA = *reinterpret_cast<const float4*>(&As[kk][ty * 4]);
            float4 aB = *reinterpret_cast<const float4*>(&As[kk][ty * 4 + 64]);
            float4 bA = *reinterpret_cast<const float4*>(&Bs[kk][tx * 4]);
            float4 bB = *reinterpret_cast<const float4*>(&Bs[kk][tx * 4 + 64]);
            float a[8] = {aA.x, aA.y, aA.z, aA.w, aB.x, aB.y, aB.z, aB.w};
            float b[8] = {bA.x, bA.y, bA.z, bA.w, bB.x, bB.y, bB.z, bB.w};
#pragma unroll
            for (int i = 0; i < 8; ++i)
#pragma unroll
                for (int j = 0; j < 8; ++j) acc[i][j] = fmaf(a[i], b[j], acc[i][j]);
        }
        __syncthreads();
    }
    const float* __restrict__ bias = b1 + (size_t)e * D_HID;
#pragma unroll
    for (int i = 0; i < 8; ++i) {
        int r = rb + ty * 4 + (i & 3) + ((i >> 2) << 6);
#pragma unroll
        for (int j = 0; j < 8; ++j) {
            int c = cb + tx * 4 + (j & 3) + ((j >> 2) << 6);
            float v = acc[i][j] + bias[c];
            v = 0.5f * v * (1.f + erff(v * 0.70710678118654752f));
            H[(size_t)r * D_HID + c] = __float2bfloat16(v);
        }
    }
}

__global__ __launch_bounds__(256) void k_gemm2(
    const __hip_bfloat16* __restrict__ H, const float* __restrict__ w2,
    const float* __restrict__ b2, const int* __restrict__ meta,
    const int* __restrict__ tileExp, const int* __restrict__ tileBase,
    float* __restrict__ Y) {
    int t = blockIdx.y;
    if (t >= meta[0]) return;
    int e = tileExp[t];
    int rb = tileBase[t];
    int cb = blockIdx.x * 128;
    const float* __restrict__ B = w2 + (size_t)e * D_HID * D_MODEL;
    __shared__ float As[16][132];
    __shared__ float Bs[16][132];
    int tid = threadIdx.x;
    int tx = tid & 15, ty = tid >> 4;
    int arow = tid >> 4, akk = tid & 15;
    int bc = tid & 127, bkr = tid >> 7;
    float acc[8][8];
#pragma unroll
    for (int i = 0; i < 8; ++i)
#pragma unroll
        for (int j = 0; j < 8; ++j) acc[i][j] = 0.f;
    for (int k0 = 0; k0 < D_HID; k0 += 16) {
#pragma unroll
        for (int p = 0; p < 8; ++p) {
            int r = rb + arow + 16 * p;
            As[akk][arow + 16 * p] = __bfloat162float(H[(size_t)r * D_HID + k0 + akk]);
        }
#pragma unroll
        for (int p = 0; p < 8; ++p) {
            int kk = bkr + 2 * p;
            Bs[kk][bc] = B[(size_t)(k0 + kk) * D_MODEL + cb + bc];
        }
        __syncthreads();
#pragma unroll
        for (int kk = 0; kk < 16; ++kk) {
            float4 aA = *reinterpret_cast<const float4*>(&As[kk][ty * 4]);
            float4 aB = *reinterpret_cast<const float4*>(&As[kk][ty * 4 + 64]);
            float4 bA = *reinterpret_cast<const float4*>(&Bs[kk][tx * 4]);
            float4 bB = *reinterpret_cast<const float4*>(&Bs[kk][tx * 4 + 64]);
            float a[8] = {aA.x, aA.y, aA.z, aA.w, aB.x, aB.y, aB.z, aB.w};
            float b[8] = {bA.x, bA.y, bA.z, bA.w, bB.x, bB.y, bB.z, bB.w};
#pragma unroll
            for (int i = 0; i < 8; ++i)
#pragma unroll
                for (int j = 0; j < 8; ++j) acc[i][j] = fmaf(a[i], b[j], acc[i][j]);
        }
        __syncthreads();
    }
    const float* __restrict__ bias = b2 + (size_t)e * D_MODEL;
#pragma unroll
    for (int i = 0; i < 8; ++i) {
        int r = rb + ty * 4 + (i & 3) + ((i >> 2) << 6);
#pragma unroll
        for (int j = 0; j < 8; ++j) {
            int c = cb + tx * 4 + (j & 3) + ((j >> 2) << 6);
            Y[(size_t)r * D_MODEL + c] = acc[i][j] + bias[c];
        }
    }
}

__global__ void k_combine_f(const float* __restrict__ Y, const int* __restrict__ slotpos,
                            const float* __restrict__ wslot, float* __restrict__ out) {
    int n = blockIdx.x;
    int p0 = slotpos[2 * n], p1 = slotpos[2 * n + 1];
    float w0 = wslot[2 * n], w1 = wslot[2 * n + 1];
    const float* y0 = Y + (size_t)p0 * D_MODEL;
    const float* y1 = Y + (size_t)p1 * D_MODEL;
    float* o = out + (size_t)n * D_MODEL;
    for (int c = threadIdx.x; c < D_MODEL; c += 256)
        o[c] = w0 * y0[c] + w1 * y1[c];
}

extern "C" void kernel_launch(void* const* d_in, const int* in_sizes, int n_in,
                              void* d_out, int out_size, void* d_ws, size_t ws_size,
                              hipStream_t stream) {
    const float* x  = (const float*)d_in[0];
    const float* gw = (const float*)d_in[1];
    const float* w1 = (const float*)d_in[2];
    const float* b1 = (const float*)d_in[3];
    const float* w2 = (const float*)d_in[4];
    const float* b2 = (const float*)d_in[5];
    float* out = (float*)d_out;
    int*   wsi = (int*)d_ws;
    float* wsf = (float*)d_ws;

    k_zero<<<1, 64, 0, stream>>>(wsi + I_COUNTS);
    k_router<<<NTOK, 64, 0, stream>>>(x, gw, wsi + I_COUNTS, wsi + I_EID, wsf + I_WSLOT);
    k_initrows<<<MAXROWS / 256, 256, 0, stream>>>(wsi + I_PERM, wsi + I_TROW);
    k_setup<<<1, 64, 0, stream>>>(wsi + I_COUNTS, wsi + I_CURSORS, wsi + I_META,
                                  wsi + I_TILEEXP, wsi + I_TILEBASE);
    k_scatter<<<(NSLOT + 255) / 256, 256, 0, stream>>>(
        wsi + I_EID, wsf + I_WSLOT, wsi + I_CURSORS, wsi + I_PERM,
        wsi + I_SLOTPOS, wsi + I_TROW, wsf + I_WROW);

    if (ws_size >= PRECONV_NEED) {
        ushort* xbf = (ushort*)((char*)d_ws + O_XBF);
        ushort* H2  = (ushort*)((char*)d_ws + O_H2);
        ushort* w1T = (ushort*)((char*)d_ws + O_W1T);
        ushort* w2T = (ushort*)((char*)d_ws + O_W2T);
        ushort* Yp  = (ushort*)((char*)d_ws + O_YP);    // overlays w1T (dead after gemm1)
        k_cvt_x<<<(NTOK * D_MODEL / 4) / 256, 256, 0, stream>>>(x, xbf);
        k_cvt_wT<<<dim3(D_HID / 64, D_MODEL / 64, NE), 256, 0, stream>>>(w1, w1T, D_MODEL, D_HID);
        k_cvt_wT<<<dim3(D_MODEL / 64, D_HID / 64, NE), 256, 0, stream>>>(w2, w2T, D_HID, D_MODEL);
        k_gemm1_mfma<<<(D_HID / 128) * MAXTILES, 256, 0, stream>>>(
            xbf, w1T, b1, wsi + I_META, wsi + I_TILEEXP, wsi + I_TILEBASE,
            wsi + I_TROW, H2);
        k_gemm2_mfma<<<(D_MODEL / 128) * (2 * MAXTILES) * 4, 256, 0, stream>>>(
            H2, w2T, b2, wsi + I_META, wsi + I_TILEBASE, wsi + I_TILEEXP, Yp);
        k_combine<<<NTOK, 192, 0, stream>>>(Yp, wsi + I_SLOTPOS, wsf + I_WSLOT, out);
    } else {
        __hip_bfloat16* H = (__hip_bfloat16*)((char*)d_ws + F_H_BYTES);
        float*          Y = (float*)((char*)d_ws + F_Y_BYTES);
        k_gemm1<<<dim3(D_HID / 128, MAXTILES), 256, 0, stream>>>(
            x, w1, b1, wsi + I_META, wsi + I_TILEEXP, wsi + I_TILEBASE,
            wsi + I_PERM, H);
        k_gemm2<<<dim3(D_MODEL / 128, MAXTILES), 256, 0, stream>>>(
            H, w2, b2, wsi + I_META, wsi + I_TILEEXP, wsi + I_TILEBASE, Y);
        k_combine_f<<<NTOK, 256, 0, stream>>>(Y, wsi + I_SLOTPOS, wsf + I_WSLOT, out);
    }
}

// Round 7
// 371.413 us; speedup vs baseline: 1.4615x; 1.4465x over previous
//
#include <hip/hip_runtime.h>
#include <hip/hip_bf16.h>
#include <math.h>

#define D_MODEL 768
#define D_HID   3072
#define NE      8
#define NTOK    2048
#define NSLOT   (NTOK * 2)
#define RT      128
#define MAXTILES 40
#define MAXROWS  5120

typedef __attribute__((ext_vector_type(8))) short short8;
typedef __attribute__((ext_vector_type(4))) float f32x4;
typedef unsigned short ushort;
typedef unsigned int uint;

// ---- int-region layout (in int units, < 1 MB total) ----
#define I_COUNTS   0
#define I_CURSORS  8
#define I_META     16
#define I_TILEEXP  32
#define I_TILEBASE 72
#define I_PERM     128        // 5120
#define I_SLOTPOS  5248       // 4096
#define I_EID      9344       // 4096
#define I_WSLOT    13440      // 4096 floats
#define I_TROW     17536      // 5120: padded-row -> token (-1 = pad)
#define I_WROW     22656      // 5120 floats (fallback only)
// ---- byte offsets, preconv (MFMA) path ----
#define O_XBF   ((size_t)1 << 20)    // 2048x768 bf16 = 3 MB
#define O_H2    ((size_t)4 << 20)    // 5120x3072 bf16 = 30 MB
#define O_W1T   ((size_t)36 << 20)   // [8][3072][768] bf16 = 36 MB (dead after gemm1)
#define O_YP    ((size_t)36 << 20)   // 4 x bf16 [5120][768] partials = 30 MB, overlays w1T
#define O_W2T   ((size_t)72 << 20)   // [8][768][3072] bf16 = 36 MB
#define PRECONV_NEED ((size_t)108 << 20)
#define YPS     ((size_t)MAXROWS * D_MODEL)    // partial-buffer stride in ushorts
// ---- fallback path byte offsets ----
#define F_H_BYTES  ((size_t)1 << 20)
#define F_Y_BYTES  ((size_t)33 << 20)

__device__ inline ushort f2bf(float f) {   // RNE fp32 -> bf16 bits
    uint u = __float_as_uint(f);
    return (ushort)((u + 0x7fffu + ((u >> 16) & 1u)) >> 16);
}
__device__ inline float bf2f(ushort u) {
    return __uint_as_float(((uint)u) << 16);
}

// async global->LDS, 16 B per lane; lds base must be wave-uniform (HW adds lane*16)
__device__ inline void gload16(const ushort* g, ushort* l) {
    __builtin_amdgcn_global_load_lds(
        (const __attribute__((address_space(1))) uint*)g,
        (__attribute__((address_space(3))) uint*)l, 16, 0, 0);
}

__global__ void k_zero(int* counts) {
    if (threadIdx.x < NE) counts[threadIdx.x] = 0;
}

__global__ void k_initrows(int* __restrict__ perm, int* __restrict__ trow) {
    int i = blockIdx.x * 256 + threadIdx.x;    // 20*256 = 5120 exact
    perm[i] = -1;
    trow[i] = -1;
}

__global__ void k_router(const float* __restrict__ x, const float* __restrict__ gw,
                         int* __restrict__ counts, int* __restrict__ eid,
                         float* __restrict__ wslot) {
    int n = blockIdx.x;
    int lane = threadIdx.x;
    const float* xr = x + (size_t)n * D_MODEL;
    float acc[NE];
#pragma unroll
    for (int e = 0; e < NE; ++e) acc[e] = 0.f;
    for (int d = lane; d < D_MODEL; d += 64) {
        float xv = xr[d];
        const float* g = gw + (size_t)d * NE;
#pragma unroll
        for (int e = 0; e < NE; ++e) acc[e] += xv * g[e];
    }
#pragma unroll
    for (int e = 0; e < NE; ++e) {
        float v = acc[e];
        for (int off = 32; off; off >>= 1) v += __shfl_down(v, off);
        acc[e] = v;
    }
    if (lane == 0) {
        int e1 = 0; float l1 = acc[0];
        for (int e = 1; e < NE; ++e) if (acc[e] > l1) { l1 = acc[e]; e1 = e; }
        int e2 = -1; float l2 = -1e30f;
        for (int e = 0; e < NE; ++e) if (e != e1 && acc[e] > l2) { l2 = acc[e]; e2 = e; }
        float wa = 1.f / (1.f + expf(l2 - l1));
        float wb = 1.f / (1.f + expf(l1 - l2));
        eid[2 * n] = e1;   eid[2 * n + 1] = e2;
        wslot[2 * n] = wa; wslot[2 * n + 1] = wb;
        atomicAdd(&counts[e1], 1);
        atomicAdd(&counts[e2], 1);
    }
}

__global__ void k_setup(const int* __restrict__ counts, int* __restrict__ cursors,
                        int* __restrict__ meta, int* __restrict__ tileExp,
                        int* __restrict__ tileBase) {
    if (threadIdx.x == 0) {
        int off = 0, nt = 0;
        for (int e = 0; e < NE; ++e) {
            cursors[e] = off;
            int t = (counts[e] + RT - 1) / RT;
            for (int i = 0; i < t; ++i) { tileExp[nt] = e; tileBase[nt] = off + i * RT; ++nt; }
            off += t * RT;
        }
        meta[0] = nt;
        meta[1] = off;
    }
}

__global__ void k_scatter(const int* __restrict__ eid, const float* __restrict__ wslot,
                          int* __restrict__ cursors, int* __restrict__ perm,
                          int* __restrict__ slotpos, int* __restrict__ trow,
                          float* __restrict__ wrow) {
    int i = blockIdx.x * 256 + threadIdx.x;
    if (i >= NSLOT) return;
    int e = eid[i];
    int pos = atomicAdd(&cursors[e], 1);
    perm[pos] = i;
    slotpos[i] = pos;
    trow[pos] = i >> 1;
    wrow[pos] = wslot[i];
}

// ---------------- convert passes (preconv path) ----------------

__global__ void k_cvt_x(const float* __restrict__ x, ushort* __restrict__ xbf) {
    int i = blockIdx.x * 256 + threadIdx.x;        // over float4s, exact
    float4 v = reinterpret_cast<const float4*>(x)[i];
    ushort4 o = { f2bf(v.x), f2bf(v.y), f2bf(v.z), f2bf(v.w) };
    reinterpret_cast<ushort4*>(xbf)[i] = o;
}

// [E][K][N] fp32 -> [E][N][K] bf16, 64x64 tiles
__global__ __launch_bounds__(256) void k_cvt_wT(const float* __restrict__ src,
                                                ushort* __restrict__ dst,
                                                int K, int N) {
    __shared__ ushort tile[64][68];   // 68: row stride 34 words -> kc-group conflicts ~4-way not 8
    int e = blockIdx.z;
    int n0 = blockIdx.x * 64, k0 = blockIdx.y * 64;
    const float* S = src + (size_t)e * K * N;
    ushort* D = dst + (size_t)e * N * K;
    int t = threadIdx.x;
#pragma unroll
    for (int i = 0; i < 4; ++i) {
        int li = t + 256 * i;          // 0..1023
        int kr = li >> 4;              // 0..63
        int nc = (li & 15) * 4;
        float4 v = *reinterpret_cast<const float4*>(S + (size_t)(k0 + kr) * N + n0 + nc);
        tile[kr][nc + 0] = f2bf(v.x);
        tile[kr][nc + 1] = f2bf(v.y);
        tile[kr][nc + 2] = f2bf(v.z);
        tile[kr][nc + 3] = f2bf(v.w);
    }
    __syncthreads();
#pragma unroll
    for (int i = 0; i < 2; ++i) {
        int li = t + 256 * i;          // 0..511
        int nr = li >> 3;              // 0..63
        int kc = (li & 7) * 8;
        ushort o[8];
#pragma unroll
        for (int j = 0; j < 8; ++j) o[j] = tile[kc + j][nr];
        *reinterpret_cast<uint4*>(D + (size_t)(n0 + nr) * K + k0 + kc) =
            *reinterpret_cast<const uint4*>(o);
    }
}

// ---------------- MFMA GEMMs ----------------
// Staging: global_load_lds dwordx4 into LINEAR LDS; the XOR swizzle lives in the
// per-lane GLOBAL source address (m173 pattern): within each 8-row stripe, lane l
// fetches chunk (l&7)^(l>>3) of row (l>>3). LDS(row,ch) thus holds global chunk
// ch^(row&7), matching the verified swizzled read side (rule #21). Coalescing
// preserved: 8 lanes permute chunks within one 128 B row segment.
// XCD swizzle (T1): flat grid, nwg % 8 == 0, swz = (bid&7)*(nwg/8) + (bid>>3).

#define MFMA16(a, b, c) __builtin_amdgcn_mfma_f32_16x16x32_bf16(a, b, c, 0, 0, 0)

// GEMM1: H[r, :] = gelu(xbf[tok(r)] @ w1T^T + b1)   (128x128 tile, 4 waves 2x2)
__global__ __launch_bounds__(256) void k_gemm1_mfma(
    const ushort* __restrict__ xbf, const ushort* __restrict__ w1T,
    const float* __restrict__ b1, const int* __restrict__ meta,
    const int* __restrict__ tileExp, const int* __restrict__ tileBase,
    const int* __restrict__ trow, ushort* __restrict__ H) {
    const int NWG = (D_HID / 128) * MAXTILES;        // 960
    int bid = blockIdx.x;
    int swz = (bid & 7) * (NWG / 8) + (bid >> 3);    // t-major chunks per XCD
    int t = swz / (D_HID / 128);
    int cb = (swz % (D_HID / 128)) * 128;
    if (t >= meta[0]) return;
    int e = tileExp[t], rb = tileBase[t];
    const ushort* __restrict__ B = w1T + (size_t)e * D_HID * D_MODEL;   // [3072][768]

    __shared__ ushort Alds[128 * 64];
    __shared__ ushort Blds[128 * 64];

    int tid = threadIdx.x;
    int lane = tid & 63, w = tid >> 6;

    // staging sources: 4 instrs per wave per matrix, 8 rows each
    const ushort* asrc[4];
    const ushort* bsrc[4];
    ushort* adst[4];
    ushort* bdst[4];
    int sc = (lane & 7) ^ (lane >> 3);               // pre-swizzled source chunk
#pragma unroll
    for (int i = 0; i < 4; ++i) {
        int stripe = w * 4 + i;                      // 0..15
        int r = stripe * 8 + (lane >> 3);            // 0..127
        int tk = trow[rb + r];
        if (tk < 0) tk = 0;                          // pad rows: finite garbage, never combined
        asrc[i] = xbf + (size_t)tk * D_MODEL + sc * 8;
        bsrc[i] = B + (size_t)(cb + r) * D_MODEL + sc * 8;
        adst[i] = Alds + stripe * 512;               // wave-uniform base (512 ushorts = 1 KB)
        bdst[i] = Blds + stripe * 512;
    }

    int wr = w >> 1, wc = w & 1;
    const ushort* aRd = Alds + (wr * 64 + (lane & 15)) * 64;
    const ushort* bRd = Blds + (wc * 64 + (lane & 15)) * 64;
    int swz0 = (((lane >> 4)) ^ (lane & 7)) * 8;
    int swz1 = ((4 + (lane >> 4)) ^ (lane & 7)) * 8;

    f32x4 acc[4][4];
#pragma unroll
    for (int i = 0; i < 4; ++i)
#pragma unroll
        for (int j = 0; j < 4; ++j) acc[i][j] = (f32x4){0.f, 0.f, 0.f, 0.f};

    for (int k0 = 0; k0 < D_MODEL; k0 += 64) {
        __syncthreads();                             // prev compute done, LDS free
#pragma unroll
        for (int i = 0; i < 4; ++i) gload16(asrc[i] + k0, adst[i]);
#pragma unroll
        for (int i = 0; i < 4; ++i) gload16(bsrc[i] + k0, bdst[i]);
        asm volatile("s_waitcnt vmcnt(0)" ::: "memory");
        __syncthreads();
#pragma unroll
        for (int ks = 0; ks < 2; ++ks) {
            int swzo = ks ? swz1 : swz0;
            short8 af[4], bfv[4];
#pragma unroll
            for (int fm = 0; fm < 4; ++fm)
                af[fm] = *reinterpret_cast<const short8*>(aRd + fm * 16 * 64 + swzo);
#pragma unroll
            for (int fn = 0; fn < 4; ++fn)
                bfv[fn] = *reinterpret_cast<const short8*>(bRd + fn * 16 * 64 + swzo);
#pragma unroll
            for (int fm = 0; fm < 4; ++fm)
#pragma unroll
                for (int fn = 0; fn < 4; ++fn)
                    acc[fm][fn] = MFMA16(af[fm], bfv[fn], acc[fm][fn]);
        }
    }

    const float* __restrict__ bias = b1 + (size_t)e * D_HID;
    int r0 = rb + wr * 64, c0 = cb + wc * 64;
#pragma unroll
    for (int fm = 0; fm < 4; ++fm) {
#pragma unroll
        for (int j = 0; j < 4; ++j) {
            int R = r0 + fm * 16 + (lane >> 4) * 4 + j;
#pragma unroll
            for (int fn = 0; fn < 4; ++fn) {
                int C = c0 + fn * 16 + (lane & 15);
                float v = acc[fm][fn][j] + bias[C];
                v = 0.5f * v * (1.f + erff(v * 0.70710678118654752f));
                H[(size_t)R * D_HID + C] = f2bf(v);
            }
        }
    }
}

// GEMM2 split-K=4: Yp[kc][r, :] = H[r, kc*768:(kc+1)*768] @ w2T^T (+b2 if kc==0), bf16
// 64x128 tile, 4 waves 2x2
__global__ __launch_bounds__(256) void k_gemm2_mfma(
    const ushort* __restrict__ H, const ushort* __restrict__ w2T,
    const float* __restrict__ b2, const int* __restrict__ meta,
    const int* __restrict__ tileBase, const int* __restrict__ tileExp,
    ushort* __restrict__ Yp) {
    const int NWG = (D_MODEL / 128) * (2 * MAXTILES) * 4;   // 1920
    int bid = blockIdx.x;
    int swz = (bid & 7) * (NWG / 8) + (bid >> 3);
    int kc  = swz / 480;
    int rem = swz % 480;
    int tt  = rem / 6;
    int cb  = (rem % 6) * 128;
    int t = tt >> 1;
    if (t >= meta[0]) return;
    int e = tileExp[t];
    int rb = tileBase[t] + (tt & 1) * 64;
    int kbase = kc * 768;
    const ushort* __restrict__ B = w2T + (size_t)e * D_MODEL * D_HID;   // [768][3072]

    __shared__ ushort Alds[64 * 64];
    __shared__ ushort Blds[128 * 64];

    int tid = threadIdx.x;
    int lane = tid & 63, w = tid >> 6;

    const ushort* asrc[2];
    const ushort* bsrc[4];
    ushort* adst[2];
    ushort* bdst[4];
    int sc = (lane & 7) ^ (lane >> 3);
#pragma unroll
    for (int i = 0; i < 2; ++i) {
        int stripe = w * 2 + i;                      // 0..7
        int r = stripe * 8 + (lane >> 3);            // 0..63
        asrc[i] = H + (size_t)(rb + r) * D_HID + kbase + sc * 8;
        adst[i] = Alds + stripe * 512;
    }
#pragma unroll
    for (int i = 0; i < 4; ++i) {
        int stripe = w * 4 + i;                      // 0..15
        int r = stripe * 8 + (lane >> 3);            // 0..127
        bsrc[i] = B + (size_t)(cb + r) * D_HID + kbase + sc * 8;
        bdst[i] = Blds + stripe * 512;
    }

    int wr = w >> 1, wc = w & 1;
    const ushort* aRd = Alds + (wr * 32 + (lane & 15)) * 64;
    const ushort* bRd = Blds + (wc * 64 + (lane & 15)) * 64;
    int swz0 = (((lane >> 4)) ^ (lane & 7)) * 8;
    int swz1 = ((4 + (lane >> 4)) ^ (lane & 7)) * 8;

    f32x4 acc[2][4];
#pragma unroll
    for (int i = 0; i < 2; ++i)
#pragma unroll
        for (int j = 0; j < 4; ++j) acc[i][j] = (f32x4){0.f, 0.f, 0.f, 0.f};

    for (int k0 = 0; k0 < 768; k0 += 64) {
        __syncthreads();
#pragma unroll
        for (int i = 0; i < 2; ++i) gload16(asrc[i] + k0, adst[i]);
#pragma unroll
        for (int i = 0; i < 4; ++i) gload16(bsrc[i] + k0, bdst[i]);
        asm volatile("s_waitcnt vmcnt(0)" ::: "memory");
        __syncthreads();
#pragma unroll
        for (int ks = 0; ks < 2; ++ks) {
            int swzo = ks ? swz1 : swz0;
            short8 af[2], bfv[4];
#pragma unroll
            for (int fm = 0; fm < 2; ++fm)
                af[fm] = *reinterpret_cast<const short8*>(aRd + fm * 16 * 64 + swzo);
#pragma unroll
            for (int fn = 0; fn < 4; ++fn)
                bfv[fn] = *reinterpret_cast<const short8*>(bRd + fn * 16 * 64 + swzo);
#pragma unroll
            for (int fm = 0; fm < 2; ++fm)
#pragma unroll
                for (int fn = 0; fn < 4; ++fn)
                    acc[fm][fn] = MFMA16(af[fm], bfv[fn], acc[fm][fn]);
        }
    }

    const float* __restrict__ bias = b2 + (size_t)e * D_MODEL;
    ushort* __restrict__ Yk = Yp + (size_t)kc * YPS;
    int r0 = rb + wr * 32, c0 = cb + wc * 64;
#pragma unroll
    for (int fm = 0; fm < 2; ++fm) {
#pragma unroll
        for (int j = 0; j < 4; ++j) {
            int R = r0 + fm * 16 + (lane >> 4) * 4 + j;
            ushort* yrow = Yk + (size_t)R * D_MODEL;
#pragma unroll
            for (int fn = 0; fn < 4; ++fn) {
                int C = c0 + fn * 16 + (lane & 15);
                float bb = (kc == 0) ? bias[C] : 0.f;
                yrow[C] = f2bf(acc[fm][fn][j] + bb);
            }
        }
    }
}

// out[n] = w0 * sum_kc Yp[kc][p0] + w1 * sum_kc Yp[kc][p1]
__global__ void k_combine(const ushort* __restrict__ Yp, const int* __restrict__ slotpos,
                          const float* __restrict__ wslot, float* __restrict__ out) {
    int n = blockIdx.x;
    int c = threadIdx.x;                 // 192 threads x 4 cols
    int p0 = slotpos[2 * n], p1 = slotpos[2 * n + 1];
    float w0 = wslot[2 * n], w1 = wslot[2 * n + 1];
    float s0[4] = {0.f, 0.f, 0.f, 0.f};
    float s1[4] = {0.f, 0.f, 0.f, 0.f};
#pragma unroll
    for (int kc = 0; kc < 4; ++kc) {
        const ushort* Yk = Yp + (size_t)kc * YPS;
        ushort4 u0 = *reinterpret_cast<const ushort4*>(Yk + (size_t)p0 * D_MODEL + c * 4);
        ushort4 u1 = *reinterpret_cast<const ushort4*>(Yk + (size_t)p1 * D_MODEL + c * 4);
        s0[0] += bf2f(u0.x); s0[1] += bf2f(u0.y); s0[2] += bf2f(u0.z); s0[3] += bf2f(u0.w);
        s1[0] += bf2f(u1.x); s1[1] += bf2f(u1.y); s1[2] += bf2f(u1.z); s1[3] += bf2f(u1.w);
    }
    float4 o = make_float4(w0 * s0[0] + w1 * s1[0], w0 * s0[1] + w1 * s1[1],
                           w0 * s0[2] + w1 * s1[2], w0 * s0[3] + w1 * s1[3]);
    *reinterpret_cast<float4*>(out + (size_t)n * D_MODEL + c * 4) = o;
}

// ---------------- fallback SIMT path (round-1, verified) ----------------

__global__ __launch_bounds__(256) void k_gemm1(
    const float* __restrict__ x, const float* __restrict__ w1,
    const float* __restrict__ b1, const int* __restrict__ meta,
    const int* __restrict__ tileExp, const int* __restrict__ tileBase,
    const int* __restrict__ perm, __hip_bfloat16* __restrict__ H) {
    int t = blockIdx.y;
    if (t >= meta[0]) return;
    int e = tileExp[t];
    int rb = tileBase[t];
    int cb = blockIdx.x * 128;
    const float* __restrict__ B = w1 + (size_t)e * D_MODEL * D_HID;
    __shared__ float As[16][132];
    __shared__ float Bs[16][132];
    int tid = threadIdx.x;
    int tx = tid & 15, ty = tid >> 4;
    int arow = tid >> 4, akk = tid & 15;
    int bc = tid & 127, bkr = tid >> 7;
    int tok[8];
#pragma unroll
    for (int p = 0; p < 8; ++p) {
        int s = perm[rb + arow + 16 * p];
        tok[p] = (s >= 0) ? (s >> 1) : -1;
    }
    float acc[8][8];
#pragma unroll
    for (int i = 0; i < 8; ++i)
#pragma unroll
        for (int j = 0; j < 8; ++j) acc[i][j] = 0.f;
    for (int k0 = 0; k0 < D_MODEL; k0 += 16) {
#pragma unroll
        for (int p = 0; p < 8; ++p) {
            float v = 0.f;
            if (tok[p] >= 0) v = x[(size_t)tok[p] * D_MODEL + k0 + akk];
            As[akk][arow + 16 * p] = v;
        }
#pragma unroll
        for (int p = 0; p < 8; ++p) {
            int kk = bkr + 2 * p;
            Bs[kk][bc] = B[(size_t)(k0 + kk) * D_HID + cb + bc];
        }
        __syncthreads();
#pragma unroll
        for (int kk = 0; kk < 16; ++kk) {
            float4 aA = *reinterpret_cast<const float4*>(&As[kk][ty * 4]);
            float4 aB = *reinterpret_cast<const float4*>(&As[kk][ty * 4 + 64]);
            float4 bA = *reinterpret_cast<const float4*>(&Bs[kk][tx * 4]);
            float4 bB = *reinterpret_cast<const float4*>(&Bs[kk][tx * 4 + 64]);
            float a[8] = {aA.x, aA.y, aA.z, aA.w, aB.x, aB.y, aB.z, aB.w};
            float b[8] = {bA.x, bA.y, bA.z, bA.w, bB.x, bB.y, bB.z, bB.w};
#pragma unroll
            for (int i = 0; i < 8; ++i)
#pragma unroll
                for (int j = 0; j < 8; ++j) acc[i][j] = fmaf(a[i], b[j], acc[i][j]);
        }
        __syncthreads();
    }
    const float* __restrict__ bias = b1 + (size_t)e * D_HID;
#pragma unroll
    for (int i = 0; i < 8; ++i) {
        int r = rb + ty * 4 + (i & 3) + ((i >> 2) << 6);
#pragma unroll
        for (int j = 0; j < 8; ++j) {
            int c = cb + tx * 4 + (j & 3) + ((j >> 2) << 6);
            float v = acc[i][j] + bias[c];
            v = 0.5f * v * (1.f + erff(v * 0.70710678118654752f));
            H[(size_t)r * D_HID + c] = __float2bfloat16(v);
        }
    }
}

__global__ __launch_bounds__(256) void k_gemm2(
    const __hip_bfloat16* __restrict__ H, const float* __restrict__ w2,
    const float* __restrict__ b2, const int* __restrict__ meta,
    const int* __restrict__ tileExp, const int* __restrict__ tileBase,
    float* __restrict__ Y) {
    int t = blockIdx.y;
    if (t >= meta[0]) return;
    int e = tileExp[t];
    int rb = tileBase[t];
    int cb = blockIdx.x * 128;
    const float* __restrict__ B = w2 + (size_t)e * D_HID * D_MODEL;
    __shared__ float As[16][132];
    __shared__ float Bs[16][132];
    int tid = threadIdx.x;
    int tx = tid & 15, ty = tid >> 4;
    int arow = tid >> 4, akk = tid & 15;
    int bc = tid & 127, bkr = tid >> 7;
    float acc[8][8];
#pragma unroll
    for (int i = 0; i < 8; ++i)
#pragma unroll
        for (int j = 0; j < 8; ++j) acc[i][j] = 0.f;
    for (int k0 = 0; k0 < D_HID; k0 += 16) {
#pragma unroll
        for (int p = 0; p < 8; ++p) {
            int r = rb + arow + 16 * p;
            As[akk][arow + 16 * p] = __bfloat162float(H[(size_t)r * D_HID + k0 + akk]);
        }
#pragma unroll
        for (int p = 0; p < 8; ++p) {
            int kk = bkr + 2 * p;
            Bs[kk][bc] = B[(size_t)(k0 + kk) * D_MODEL + cb + bc];
        }
        __syncthreads();
#pragma unroll
        for (int kk = 0; kk < 16; ++kk) {
            float4 aA = *reinterpret_cast<const float4*>(&As[kk][ty * 4]);
            float4 aB = *reinterpret_cast<const float4*>(&As[kk][ty * 4 + 64]);
            float4 bA = *reinterpret_cast<const float4*>(&Bs[kk][tx * 4]);
            float4 bB = *reinterpret_cast<const float4*>(&Bs[kk][tx * 4 + 64]);
            float a[8] = {aA.x, aA.y, aA.z, aA.w, aB.x, aB.y, aB.z, aB.w};
            float b[8] = {bA.x, bA.y, bA.z, bA.w, bB.x, bB.y, bB.z, bB.w};
#pragma unroll
            for (int i = 0; i < 8; ++i)
#pragma unroll
                for (int j = 0; j < 8; ++j) acc[i][j] = fmaf(a[i], b[j], acc[i][j]);
        }
        __syncthreads();
    }
    const float* __restrict__ bias = b2 + (size_t)e * D_MODEL;
#pragma unroll
    for (int i = 0; i < 8; ++i) {
        int r = rb + ty * 4 + (i & 3) + ((i >> 2) << 6);
#pragma unroll
        for (int j = 0; j < 8; ++j) {
            int c = cb + tx * 4 + (j & 3) + ((j >> 2) << 6);
            Y[(size_t)r * D_MODEL + c] = acc[i][j] + bias[c];
        }
    }
}

__global__ void k_combine_f(const float* __restrict__ Y, const int* __restrict__ slotpos,
                            const float* __restrict__ wslot, float* __restrict__ out) {
    int n = blockIdx.x;
    int p0 = slotpos[2 * n], p1 = slotpos[2 * n + 1];
    float w0 = wslot[2 * n], w1 = wslot[2 * n + 1];
    const float* y0 = Y + (size_t)p0 * D_MODEL;
    const float* y1 = Y + (size_t)p1 * D_MODEL;
    float* o = out + (size_t)n * D_MODEL;
    for (int c = threadIdx.x; c < D_MODEL; c += 256)
        o[c] = w0 * y0[c] + w1 * y1[c];
}

extern "C" void kernel_launch(void* const* d_in, const int* in_sizes, int n_in,
                              void* d_out, int out_size, void* d_ws, size_t ws_size,
                              hipStream_t stream) {
    const float* x  = (const float*)d_in[0];
    const float* gw = (const float*)d_in[1];
    const float* w1 = (const float*)d_in[2];
    const float* b1 = (const float*)d_in[3];
    const float* w2 = (const float*)d_in[4];
    const float* b2 = (const float*)d_in[5];
    float* out = (float*)d_out;
    int*   wsi = (int*)d_ws;
    float* wsf = (float*)d_ws;

    k_zero<<<1, 64, 0, stream>>>(wsi + I_COUNTS);
    k_router<<<NTOK, 64, 0, stream>>>(x, gw, wsi + I_COUNTS, wsi + I_EID, wsf + I_WSLOT);
    k_initrows<<<MAXROWS / 256, 256, 0, stream>>>(wsi + I_PERM, wsi + I_TROW);
    k_setup<<<1, 64, 0, stream>>>(wsi + I_COUNTS, wsi + I_CURSORS, wsi + I_META,
                                  wsi + I_TILEEXP, wsi + I_TILEBASE);
    k_scatter<<<(NSLOT + 255) / 256, 256, 0, stream>>>(
        wsi + I_EID, wsf + I_WSLOT, wsi + I_CURSORS, wsi + I_PERM,
        wsi + I_SLOTPOS, wsi + I_TROW, wsf + I_WROW);

    if (ws_size >= PRECONV_NEED) {
        ushort* xbf = (ushort*)((char*)d_ws + O_XBF);
        ushort* H2  = (ushort*)((char*)d_ws + O_H2);
        ushort* w1T = (ushort*)((char*)d_ws + O_W1T);
        ushort* w2T = (ushort*)((char*)d_ws + O_W2T);
        ushort* Yp  = (ushort*)((char*)d_ws + O_YP);    // overlays w1T (dead after gemm1)
        k_cvt_x<<<(NTOK * D_MODEL / 4) / 256, 256, 0, stream>>>(x, xbf);
        k_cvt_wT<<<dim3(D_HID / 64, D_MODEL / 64, NE), 256, 0, stream>>>(w1, w1T, D_MODEL, D_HID);
        k_cvt_wT<<<dim3(D_MODEL / 64, D_HID / 64, NE), 256, 0, stream>>>(w2, w2T, D_HID, D_MODEL);
        k_gemm1_mfma<<<(D_HID / 128) * MAXTILES, 256, 0, stream>>>(
            xbf, w1T, b1, wsi + I_META, wsi + I_TILEEXP, wsi + I_TILEBASE,
            wsi + I_TROW, H2);
        k_gemm2_mfma<<<(D_MODEL / 128) * (2 * MAXTILES) * 4, 256, 0, stream>>>(
            H2, w2T, b2, wsi + I_META, wsi + I_TILEBASE, wsi + I_TILEEXP, Yp);
        k_combine<<<NTOK, 192, 0, stream>>>(Yp, wsi + I_SLOTPOS, wsf + I_WSLOT, out);
    } else {
        __hip_bfloat16* H = (__hip_bfloat16*)((char*)d_ws + F_H_BYTES);
        float*          Y = (float*)((char*)d_ws + F_Y_BYTES);
        k_gemm1<<<dim3(D_HID / 128, MAXTILES), 256, 0, stream>>>(
            x, w1, b1, wsi + I_META, wsi + I_TILEEXP, wsi + I_TILEBASE,
            wsi + I_PERM, H);
        k_gemm2<<<dim3(D_MODEL / 128, MAXTILES), 256, 0, stream>>>(
            H, w2, b2, wsi + I_META, wsi + I_TILEEXP, wsi + I_TILEBASE, Y);
        k_combine_f<<<NTOK, 256, 0, stream>>>(Y, wsi + I_SLOTPOS, wsf + I_WSLOT, out);
    }
}